// Round 5
// baseline (1229.582 us; speedup 1.0000x reference)
//
#include <hip/hip_runtime.h>

// Attention2: point-cloud attention, N=1M, KNN=9, C_in=C_inner=20, REPEAT=2.
// R4: conv1 is affine -> y[n,k] = u[idx]-v[n]; u precomputed (k0), v cheap.
// R5 FAILED: array-ref helper -> scratch (2.3 GB phantom traffic).
// R6 FAILED: cat[40] under (256,3) demoted to scratch (VGPR=84, 1.9 GB).
// R7 WIN: k6 on k0's proven shape (plain (256), one pt/thread, two 20x20
// halves) -> k6 805 -> ~55 us; total 1043 us. Lesson: keep per-thread
// arrays single-phase, plain launch bounds for streaming matmul kernels.
// R8 (this round): gather passes now dominate (k3 258 us, FETCH 590 MB vs
// 176 ideal). Two padded-layout diseases: (1) RFO — storerow20 covers only
// 80 of each 128-B line, L2 must fetch the line before merge (+128 MB fetch
// in k3, same in k0); (2) L3 thrash — padded u+xagg = 256 MB + 84 MB misc
// > 256 MB Infinity Cache, so u's 9x reuse misses to HBM. Fix: COMPACT
// 80-B rows everywhere (us=as=20). Dense stores (no RFO); k3 working set
// 244 MB < L3; k1 warms u (128 MB ws) so k3 gathers hit L3. Straddle
// (~1.5 lines/gather) only costs on a miss; rows stay 16-B aligned.
// Register discipline: (256,3) on gather kernels — NOT (256,4) (64-reg
// clamp + 12 GB spill, R2); streaming matmuls plain (256).

constexpr int KNN_ = 9;
constexpr int CI   = 20;
constexpr int CC   = 23;
constexpr int CAT  = 40;
constexpr float EPS = 1e-5f;

template <int CNT>
__device__ __forceinline__ void block_reduce_add(float (&v)[CNT], double* __restrict__ dst,
                                                 float* __restrict__ lds /*4*CNT floats*/) {
    const int lane = threadIdx.x & 63;
    const int wid  = threadIdx.x >> 6;
#pragma unroll
    for (int i = 0; i < CNT; ++i) {
        float x = v[i];
#pragma unroll
        for (int off = 32; off > 0; off >>= 1) x += __shfl_down(x, off);
        if (lane == 0) lds[wid * CNT + i] = x;
    }
    __syncthreads();
    if (threadIdx.x < CNT) {
        float x = lds[threadIdx.x] + lds[CNT + threadIdx.x] +
                  lds[2 * CNT + threadIdx.x] + lds[3 * CNT + threadIdx.x];
        atomicAdd(dst + threadIdx.x, (double)x);
    }
}

__device__ __forceinline__ void loadrow20(const float* __restrict__ p, float (&v)[CI]) {
    const float4* q = reinterpret_cast<const float4*>(p);
    const float4 a = q[0], b = q[1], c = q[2], d = q[3], e = q[4];
    v[0]=a.x; v[1]=a.y; v[2]=a.z; v[3]=a.w;
    v[4]=b.x; v[5]=b.y; v[6]=b.z; v[7]=b.w;
    v[8]=c.x; v[9]=c.y; v[10]=c.z; v[11]=c.w;
    v[12]=d.x; v[13]=d.y; v[14]=d.z; v[15]=d.w;
    v[16]=e.x; v[17]=e.y; v[18]=e.z; v[19]=e.w;
}

__device__ __forceinline__ void storerow20(float* __restrict__ p, const float (&v)[CI]) {
    float4* q = reinterpret_cast<float4*>(p);
    q[0] = make_float4(v[0],  v[1],  v[2],  v[3]);
    q[1] = make_float4(v[4],  v[5],  v[6],  v[7]);
    q[2] = make_float4(v[8],  v[9],  v[10], v[11]);
    q[3] = make_float4(v[12], v[13], v[14], v[15]);
    q[4] = make_float4(v[16], v[17], v[18], v[19]);
}

// ---- K0: u[n] = W_f·feat[n] + W_x·p[n] (streamed, once per point) ----
__global__ __launch_bounds__(256) void k0_uv(
    const float* __restrict__ points, const float* __restrict__ feature,
    const float* __restrict__ W1, float* __restrict__ u, int us, int N)
{
    __shared__ float Ws[CI * CC];
    for (int i = threadIdx.x; i < CI * CC; i += 256) Ws[i] = W1[i];
    __syncthreads();
    const int n = blockIdx.x * 256 + threadIdx.x;
    if (n >= N) return;
    float in[CI];
    loadrow20(feature + (size_t)n * CI, in);
    const float px = points[3*n], py = points[3*n+1], pz = points[3*n+2];
    float uo[CI];
#pragma unroll
    for (int o = 0; o < CI; ++o) {
        float y = Ws[o*CC+20] * px;
        y = fmaf(Ws[o*CC+21], py, y);
        y = fmaf(Ws[o*CC+22], pz, y);
#pragma unroll
        for (int c = 0; c < CI; ++c) y = fmaf(Ws[o*CC+c], in[c], y);
        uo[o] = y;
    }
    storerow20(u + (size_t)n * us, uo);
}

// ---- K1: BN1 stats of y = u[idx[n,k]] - v[n] over all 9M pairs ----
__global__ __launch_bounds__(256, 3) void k1_stats(
    const float* __restrict__ points, const int* __restrict__ index,
    const float* __restrict__ W1, const float* __restrict__ u, int us,
    double* __restrict__ stats, int N)
{
    __shared__ float Ws[CI * CC];
    __shared__ float red[4 * 2 * CI];
    for (int i = threadIdx.x; i < CI * CC; i += 256) Ws[i] = W1[i];
    __syncthreads();

    float acc[2 * CI];
#pragma unroll
    for (int i = 0; i < 2 * CI; ++i) acc[i] = 0.f;

#pragma unroll 1
    for (int n = blockIdx.x * 256 + threadIdx.x; n < N; n += gridDim.x * 256) {
        const float px = points[3*n], py = points[3*n+1], pz = points[3*n+2];
        float v[CI];
#pragma unroll
        for (int o = 0; o < CI; ++o) {
            float t = Ws[o*CC+20] * px;
            t = fmaf(Ws[o*CC+21], py, t);
            v[o] = fmaf(Ws[o*CC+22], pz, t);
        }
        int idx[KNN_];
#pragma unroll
        for (int k = 0; k < KNN_; ++k) idx[k] = index[n * KNN_ + k];

#pragma unroll 1
        for (int t = 0; t < 4; ++t) {
            float ra[CI], rb[CI];
            loadrow20(u + (size_t)idx[2*t]   * us, ra);
            loadrow20(u + (size_t)idx[2*t+1] * us, rb);
#pragma unroll
            for (int o = 0; o < CI; ++o) {
                const float d = ra[o] - v[o];
                acc[o] += d;
                acc[CI + o] = fmaf(d, d, acc[CI + o]);
            }
#pragma unroll
            for (int o = 0; o < CI; ++o) {
                const float d = rb[o] - v[o];
                acc[o] += d;
                acc[CI + o] = fmaf(d, d, acc[CI + o]);
            }
        }
        {   // k = 8 tail
            float ra[CI];
            loadrow20(u + (size_t)idx[8] * us, ra);
#pragma unroll
            for (int o = 0; o < CI; ++o) {
                const float d = ra[o] - v[o];
                acc[o] += d;
                acc[CI + o] = fmaf(d, d, acc[CI + o]);
            }
        }
    }
    __syncthreads();
    block_reduce_add<2 * CI>(acc, stats, red);
}

// ---- K3: xk = u[j]*sc - v2[n]; w_k = xk·x0; xagg = Σ xk w_k ----
__global__ __launch_bounds__(256, 3) void k3_attn(
    const float* __restrict__ points, const int* __restrict__ index,
    const float* __restrict__ W1, const float* __restrict__ g1,
    const float* __restrict__ b1, const double* __restrict__ stats,
    const float* __restrict__ u, int us,
    float* __restrict__ wbuf, float* __restrict__ xagg, int as, int N)
{
    __shared__ float Ws[CI * CC];
    __shared__ float sc[CI], sh[CI];
    for (int i = threadIdx.x; i < CI * CC; i += 256) Ws[i] = W1[i];
    if (threadIdx.x < CI) {
        const double M = (double)N * KNN_;
        const double mean = stats[threadIdx.x] / M;
        const double var  = stats[CI + threadIdx.x] / M - mean * mean;
        const float s = g1[threadIdx.x] * rsqrtf((float)var + EPS);
        sc[threadIdx.x] = s;
        sh[threadIdx.x] = b1[threadIdx.x] - (float)mean * s;
    }
    __syncthreads();

    const int n = blockIdx.x * 256 + threadIdx.x;
    if (n >= N) return;

    const float px = points[3*n], py = points[3*n+1], pz = points[3*n+2];
    float v2[CI];   // v*sc - sh, so xk = u*sc - v2
#pragma unroll
    for (int o = 0; o < CI; ++o) {
        float t = Ws[o*CC+20] * px;
        t = fmaf(Ws[o*CC+21], py, t);
        t = fmaf(Ws[o*CC+22], pz, t);
        v2[o] = fmaf(t, sc[o], -sh[o]);
    }
    int idx[KNN_];
#pragma unroll
    for (int k = 0; k < KNN_; ++k) idx[k] = index[n * KNN_ + k];

    float x0[CI], accv[CI];
    {   // k = 0
        float r[CI];
        loadrow20(u + (size_t)idx[0] * us, r);
        float w0 = 0.f;
#pragma unroll
        for (int o = 0; o < CI; ++o) x0[o] = fmaf(r[o], sc[o], -v2[o]);
#pragma unroll
        for (int o = 0; o < CI; ++o) w0 = fmaf(x0[o], x0[o], w0);
        wbuf[n * KNN_] = w0;
#pragma unroll
        for (int o = 0; o < CI; ++o) accv[o] = x0[o] * w0;
    }
#pragma unroll 1
    for (int t = 0; t < 4; ++t) {
        const int ka = 1 + 2*t, kb = 2 + 2*t;
        float ra[CI], rb[CI];
        loadrow20(u + (size_t)idx[ka] * us, ra);
        loadrow20(u + (size_t)idx[kb] * us, rb);
        float wa = 0.f, wb = 0.f;
#pragma unroll
        for (int o = 0; o < CI; ++o) {
            ra[o] = fmaf(ra[o], sc[o], -v2[o]);
            wa = fmaf(ra[o], x0[o], wa);
        }
#pragma unroll
        for (int o = 0; o < CI; ++o) {
            rb[o] = fmaf(rb[o], sc[o], -v2[o]);
            wb = fmaf(rb[o], x0[o], wb);
        }
        wbuf[n * KNN_ + ka] = wa;
        wbuf[n * KNN_ + kb] = wb;
#pragma unroll
        for (int o = 0; o < CI; ++o) accv[o] = fmaf(ra[o], wa, accv[o]);
#pragma unroll
        for (int o = 0; o < CI; ++o) accv[o] = fmaf(rb[o], wb, accv[o]);
    }
    storerow20(xagg + (size_t)n * as, accv);
}

// ---- K4: x2[n] = Σ_k xagg[idx[n,k]]·w[n,k]; fused BN2 stats ----
__global__ __launch_bounds__(256, 3) void k4_prop(
    const int* __restrict__ index, const float* __restrict__ wbuf,
    const float* __restrict__ xagg, int as, float* __restrict__ x2,
    double* __restrict__ stats2, int N)
{
    __shared__ float red[4 * 2 * CI];
    float st[2 * CI];
#pragma unroll
    for (int i = 0; i < 2 * CI; ++i) st[i] = 0.f;

#pragma unroll 1
    for (int n = blockIdx.x * 256 + threadIdx.x; n < N; n += gridDim.x * 256) {
        int idx[KNN_];
        float wk[KNN_];
#pragma unroll
        for (int k = 0; k < KNN_; ++k) idx[k] = index[n * KNN_ + k];
#pragma unroll
        for (int k = 0; k < KNN_; ++k) wk[k] = wbuf[n * KNN_ + k];

        float accv[CI];
        {
            float r[CI];
            loadrow20(xagg + (size_t)idx[0] * as, r);
#pragma unroll
            for (int o = 0; o < CI; ++o) accv[o] = r[o] * wk[0];
        }
#pragma unroll 1
        for (int t = 0; t < 4; ++t) {
            const int ka = 1 + 2*t, kb = 2 + 2*t;
            float ra[CI], rb[CI];
            loadrow20(xagg + (size_t)idx[ka] * as, ra);
            loadrow20(xagg + (size_t)idx[kb] * as, rb);
#pragma unroll
            for (int o = 0; o < CI; ++o) accv[o] = fmaf(ra[o], wk[ka], accv[o]);
#pragma unroll
            for (int o = 0; o < CI; ++o) accv[o] = fmaf(rb[o], wk[kb], accv[o]);
        }
        storerow20(x2 + (size_t)n * CI, accv);
#pragma unroll
        for (int o = 0; o < CI; ++o) {
            st[o] += accv[o];
            st[CI + o] = fmaf(accv[o], accv[o], st[CI + o]);
        }
    }
    __syncthreads();
    block_reduce_add<2 * CI>(st, stats2, red);
}

// ---- K6: h=relu(bn2(x2)); ybuf = Wr1@[h,feature]+br1 ----
// R7: k0's proven shape — plain (256), one point/thread, two 20x20 dot
// halves sharing in[20]. Live ~50 floats, no arrays with >1-iter liveness.
__global__ __launch_bounds__(256) void k6_refine1(
    const float* __restrict__ x2, const float* __restrict__ feature,
    const float* __restrict__ g2, const float* __restrict__ b2,
    const float* __restrict__ Wr1, const float* __restrict__ br1,
    const double* __restrict__ stats2,
    float* __restrict__ ybuf, int N)
{
    __shared__ float Ws[CI * CAT];
    __shared__ float sc[CI], sh[CI], brs[CI];
    for (int i = threadIdx.x; i < CI * CAT; i += 256) Ws[i] = Wr1[i];
    if (threadIdx.x < CI) {
        const double M = (double)N;
        const double mean = stats2[threadIdx.x] / M;
        const double var  = stats2[CI + threadIdx.x] / M - mean * mean;
        const float s = g2[threadIdx.x] * rsqrtf((float)var + EPS);
        sc[threadIdx.x] = s;
        sh[threadIdx.x] = b2[threadIdx.x] - (float)mean * s;
        brs[threadIdx.x] = br1[threadIdx.x];
    }
    __syncthreads();

    const int n = blockIdx.x * 256 + threadIdx.x;
    if (n >= N) return;

    float in[CI];
    // phase 1: h = relu(bn2(x2)); yv = br1 + W[:,0:20]·h
    loadrow20(x2 + (size_t)n * CI, in);
#pragma unroll
    for (int o = 0; o < CI; ++o)
        in[o] = fmaxf(fmaf(in[o], sc[o], sh[o]), 0.f);
    float yv[CI];
#pragma unroll
    for (int o = 0; o < CI; ++o) {
        float y = brs[o];
#pragma unroll
        for (int c = 0; c < CI; ++c) y = fmaf(Ws[o * CAT + c], in[c], y);
        yv[o] = y;
    }
    // phase 2: yv += W[:,20:40]·feature
    loadrow20(feature + (size_t)n * CI, in);
#pragma unroll
    for (int o = 0; o < CI; ++o) {
        float y = yv[o];
#pragma unroll
        for (int c = 0; c < CI; ++c) y = fmaf(Ws[o * CAT + CI + c], in[c], y);
        yv[o] = y;
    }
    storerow20(ybuf + (size_t)n * CI, yv);
}

// ---- K7: BN3 stats over ybuf (pure streaming, 80 MB) ----
__global__ __launch_bounds__(256) void k7_stats3(
    const float* __restrict__ ybuf, double* __restrict__ stats3, int N)
{
    __shared__ float red[4 * 2 * CI];
    float st[2 * CI];
#pragma unroll
    for (int i = 0; i < 2 * CI; ++i) st[i] = 0.f;

#pragma unroll 1
    for (int n = blockIdx.x * 256 + threadIdx.x; n < N; n += gridDim.x * 256) {
        float yv[CI];
        loadrow20(ybuf + (size_t)n * CI, yv);
#pragma unroll
        for (int o = 0; o < CI; ++o) {
            st[o] += yv[o];
            st[CI + o] = fmaf(yv[o], yv[o], st[CI + o]);
        }
    }
    __syncthreads();
    block_reduce_add<2 * CI>(st, stats3, red);
}

// ---- K8: out = relu(bn3(y)) @ Wr2.T + br2 ----
__global__ __launch_bounds__(256) void k8_out(
    const float* __restrict__ ybuf,
    const float* __restrict__ g3, const float* __restrict__ b3,
    const float* __restrict__ Wr2, const float* __restrict__ br2,
    const double* __restrict__ stats3, float* __restrict__ out, int N)
{
    __shared__ float Ws[CI * CI];
    __shared__ float sc[CI], sh[CI];
    for (int i = threadIdx.x; i < CI * CI; i += 256) Ws[i] = Wr2[i];
    if (threadIdx.x < CI) {
        const double M = (double)N;
        const double mean = stats3[threadIdx.x] / M;
        const double var  = stats3[CI + threadIdx.x] / M - mean * mean;
        const float s = g3[threadIdx.x] * rsqrtf((float)var + EPS);
        sc[threadIdx.x] = s;
        sh[threadIdx.x] = b3[threadIdx.x] - (float)mean * s;
    }
    __syncthreads();

    const int n = blockIdx.x * 256 + threadIdx.x;
    if (n >= N) return;

    float z[CI];
    {
        float yi[CI];
        loadrow20(ybuf + (size_t)n * CI, yi);
#pragma unroll
        for (int o = 0; o < CI; ++o)
            z[o] = fmaxf(fmaf(yi[o], sc[o], sh[o]), 0.f);
    }
    float ov[CI];
#pragma unroll
    for (int o = 0; o < CI; ++o) {
        float y = br2[o];
#pragma unroll
        for (int c = 0; c < CI; ++c) y = fmaf(Ws[o * CI + c], z[c], y);
        ov[o] = y;
    }
    storerow20(out + (size_t)n * CI, ov);
}

extern "C" void kernel_launch(void* const* d_in, const int* in_sizes, int n_in,
                              void* d_out, int out_size, void* d_ws, size_t ws_size,
                              hipStream_t stream) {
    const float* points  = (const float*)d_in[0];
    const float* feature = (const float*)d_in[1];
    const int*   index   = (const int*)  d_in[2];
    const float* W1      = (const float*)d_in[3];
    const float* g1      = (const float*)d_in[4];
    const float* b1      = (const float*)d_in[5];
    const float* g2      = (const float*)d_in[6];
    const float* b2      = (const float*)d_in[7];
    const float* Wr1     = (const float*)d_in[8];
    const float* br1     = (const float*)d_in[9];
    const float* g3      = (const float*)d_in[10];
    const float* b3      = (const float*)d_in[11];
    const float* Wr2     = (const float*)d_in[12];
    const float* br2     = (const float*)d_in[13];
    const int N = in_sizes[0] / 3;
    float* out = (float*)d_out;

    // ws layout: [stats 1KB][wbuf N*9][u N*20][xagg N*20]; x2 aliases u
    // (dead after k3), ybuf aliases xagg (dead after k4).
    // R8: COMPACT 80-B rows (us=as=20). Dense stores -> no RFO; per-pass
    // working sets fit the 256 MB Infinity Cache (k3: 80+80+84=244 MB).
    // Total ws = 1KB + 36 MB + 160 MB = 196 MB.
    const int us = CI;
    const int as = CI;

    double* stats = (double*)d_ws;
    char* base = (char*)d_ws;
    size_t off = 1024;
    float* wbuf = (float*)(base + off); off += (size_t)N * KNN_ * 4;
    float* u    = (float*)(base + off); off += (size_t)N * us * 4;
    float* xagg = (float*)(base + off);
    float* x2   = u;     // alias: u dead after k3
    float* ybuf = xagg;  // alias: xagg dead after k4

    hipMemsetAsync(stats, 0, 6 * CI * sizeof(double), stream);

    const int B = 256;
    const int gridN = (N + B - 1) / B;
    k0_uv     <<<gridN, B, 0, stream>>>(points, feature, W1, u, us, N);
    k1_stats  <<<2048, B, 0, stream>>>(points, index, W1, u, us, stats, N);
    k3_attn   <<<gridN, B, 0, stream>>>(points, index, W1, g1, b1, stats, u, us, wbuf, xagg, as, N);
    k4_prop   <<<2048, B, 0, stream>>>(index, wbuf, xagg, as, x2, stats + 2 * CI, N);
    k6_refine1<<<gridN, B, 0, stream>>>(x2, feature, g2, b2, Wr1, br1, stats + 2 * CI, ybuf, N);
    k7_stats3 <<<2048, B, 0, stream>>>(ybuf, stats + 4 * CI, N);
    k8_out    <<<gridN, B, 0, stream>>>(ybuf, g3, b3, Wr2, br2, stats + 4 * CI, out, N);
}

// Round 6
// 974.311 us; speedup vs baseline: 1.2620x; 1.2620x over previous
//
#include <hip/hip_runtime.h>
#include <hip/hip_fp16.h>

// Attention2: point-cloud attention, N=1M, KNN=9, C_in=C_inner=20, REPEAT=2.
// R4: conv1 is affine -> y[n,k] = u[idx]-v[n]; u precomputed (k0), v cheap.
// R5 FAILED: array-ref helper -> scratch (2.3 GB phantom traffic).
// R6 FAILED: cat[40] under (256,3) demoted to scratch (VGPR=84, 1.9 GB).
// R7 WIN: k6 on k0's proven shape -> k6 805 -> ~55 us; total 1043 us.
// R8 FAILED: compact 80-B rows made k3 WORSE (FETCH 590->857 MB, 258->328us).
//   - RFO theory dead: WRITE identical (290 vs 293 MB).
//   - Thrash theory dead: smaller ws fetched MORE.
//   - Real mechanism: line straddle (80-B rows at 80-B stride: ~1.5
//     128-B lines/gather = the 1.45x fetch ratio). AND: both rounds ran at
//     the SAME ~3.55 TB/s — gathers are BYTE-bound at a random-access
//     bandwidth ceiling; duration == bytes / 3.55 TB/s. Lever = fewer bytes.
// R9 (this round): revert to padded layout (R4, proven 1043) + FP16 u table.
//   u row = 20 halves = 40 B in a 64-B slot (never straddles; table 128->64
//   MB so L2 hit rate also rises). k0 stores fp16 once; k1/k3 gather 40 B
//   and convert; all math stays fp32. BN1 stats computed from the same
//   quantized u -> self-consistent. xagg/k4 stay fp32-padded (one precision
//   variable per round). Expected: k3 fetch ~590->350, dur ~258->180.
// Register discipline: (256,3) on gather kernels; streaming matmuls plain
// (256); no array-ref helpers; all array indices compile-time.

constexpr int KNN_ = 9;
constexpr int CI   = 20;
constexpr int CC   = 23;
constexpr int CAT  = 40;
constexpr int USH  = 32;   // u row stride in halves (64 B slot)
constexpr float EPS = 1e-5f;

template <int CNT>
__device__ __forceinline__ void block_reduce_add(float (&v)[CNT], double* __restrict__ dst,
                                                 float* __restrict__ lds /*4*CNT floats*/) {
    const int lane = threadIdx.x & 63;
    const int wid  = threadIdx.x >> 6;
#pragma unroll
    for (int i = 0; i < CNT; ++i) {
        float x = v[i];
#pragma unroll
        for (int off = 32; off > 0; off >>= 1) x += __shfl_down(x, off);
        if (lane == 0) lds[wid * CNT + i] = x;
    }
    __syncthreads();
    if (threadIdx.x < CNT) {
        float x = lds[threadIdx.x] + lds[CNT + threadIdx.x] +
                  lds[2 * CNT + threadIdx.x] + lds[3 * CNT + threadIdx.x];
        atomicAdd(dst + threadIdx.x, (double)x);
    }
}

__device__ __forceinline__ void loadrow20(const float* __restrict__ p, float (&v)[CI]) {
    const float4* q = reinterpret_cast<const float4*>(p);
    const float4 a = q[0], b = q[1], c = q[2], d = q[3], e = q[4];
    v[0]=a.x; v[1]=a.y; v[2]=a.z; v[3]=a.w;
    v[4]=b.x; v[5]=b.y; v[6]=b.z; v[7]=b.w;
    v[8]=c.x; v[9]=c.y; v[10]=c.z; v[11]=c.w;
    v[12]=d.x; v[13]=d.y; v[14]=d.z; v[15]=d.w;
    v[16]=e.x; v[17]=e.y; v[18]=e.z; v[19]=e.w;
}

__device__ __forceinline__ void storerow20(float* __restrict__ p, const float (&v)[CI]) {
    float4* q = reinterpret_cast<float4*>(p);
    q[0] = make_float4(v[0],  v[1],  v[2],  v[3]);
    q[1] = make_float4(v[4],  v[5],  v[6],  v[7]);
    q[2] = make_float4(v[8],  v[9],  v[10], v[11]);
    q[3] = make_float4(v[12], v[13], v[14], v[15]);
    q[4] = make_float4(v[16], v[17], v[18], v[19]);
}

__device__ __forceinline__ float2 h2f(unsigned int u) {
    return __half22float2(__builtin_bit_cast(__half2, u));
}

// fp16 row: 20 halves (40 B) at a 64-B-aligned slot. 3 vector loads.
__device__ __forceinline__ void loadrow20h(const __half* __restrict__ p, float (&v)[CI]) {
    const uint4 A = reinterpret_cast<const uint4*>(p)[0];   // halves 0..7
    const uint4 B = reinterpret_cast<const uint4*>(p)[1];   // halves 8..15
    const uint2 C = reinterpret_cast<const uint2*>(p)[4];   // halves 16..19
    float2 f;
    f = h2f(A.x); v[0]=f.x;  v[1]=f.y;
    f = h2f(A.y); v[2]=f.x;  v[3]=f.y;
    f = h2f(A.z); v[4]=f.x;  v[5]=f.y;
    f = h2f(A.w); v[6]=f.x;  v[7]=f.y;
    f = h2f(B.x); v[8]=f.x;  v[9]=f.y;
    f = h2f(B.y); v[10]=f.x; v[11]=f.y;
    f = h2f(B.z); v[12]=f.x; v[13]=f.y;
    f = h2f(B.w); v[14]=f.x; v[15]=f.y;
    f = h2f(C.x); v[16]=f.x; v[17]=f.y;
    f = h2f(C.y); v[18]=f.x; v[19]=f.y;
}

__device__ __forceinline__ unsigned int f2h(float a, float b) {
    return __builtin_bit_cast(unsigned int, __float22half2_rn(make_float2(a, b)));
}

// store 20 floats as fp16 + zero-pad to the full 64-B slot (full coverage).
__device__ __forceinline__ void storerow20h(__half* __restrict__ p, const float (&v)[CI]) {
    uint4* q = reinterpret_cast<uint4*>(p);
    q[0] = make_uint4(f2h(v[0],v[1]),   f2h(v[2],v[3]),   f2h(v[4],v[5]),   f2h(v[6],v[7]));
    q[1] = make_uint4(f2h(v[8],v[9]),   f2h(v[10],v[11]), f2h(v[12],v[13]), f2h(v[14],v[15]));
    q[2] = make_uint4(f2h(v[16],v[17]), f2h(v[18],v[19]), 0u, 0u);
    q[3] = make_uint4(0u, 0u, 0u, 0u);
}

// ---- K0: u[n] = W_f·feat[n] + W_x·p[n] (streamed, once; fp16 out) ----
__global__ __launch_bounds__(256) void k0_uv(
    const float* __restrict__ points, const float* __restrict__ feature,
    const float* __restrict__ W1, __half* __restrict__ u, int N)
{
    __shared__ float Ws[CI * CC];
    for (int i = threadIdx.x; i < CI * CC; i += 256) Ws[i] = W1[i];
    __syncthreads();
    const int n = blockIdx.x * 256 + threadIdx.x;
    if (n >= N) return;
    float in[CI];
    loadrow20(feature + (size_t)n * CI, in);
    const float px = points[3*n], py = points[3*n+1], pz = points[3*n+2];
    float uo[CI];
#pragma unroll
    for (int o = 0; o < CI; ++o) {
        float y = Ws[o*CC+20] * px;
        y = fmaf(Ws[o*CC+21], py, y);
        y = fmaf(Ws[o*CC+22], pz, y);
#pragma unroll
        for (int c = 0; c < CI; ++c) y = fmaf(Ws[o*CC+c], in[c], y);
        uo[o] = y;
    }
    storerow20h(u + (size_t)n * USH, uo);
}

// ---- K1: BN1 stats of y = u[idx[n,k]] - v[n] over all 9M pairs ----
__global__ __launch_bounds__(256, 3) void k1_stats(
    const float* __restrict__ points, const int* __restrict__ index,
    const float* __restrict__ W1, const __half* __restrict__ u,
    double* __restrict__ stats, int N)
{
    __shared__ float Ws[CI * CC];
    __shared__ float red[4 * 2 * CI];
    for (int i = threadIdx.x; i < CI * CC; i += 256) Ws[i] = W1[i];
    __syncthreads();

    float acc[2 * CI];
#pragma unroll
    for (int i = 0; i < 2 * CI; ++i) acc[i] = 0.f;

#pragma unroll 1
    for (int n = blockIdx.x * 256 + threadIdx.x; n < N; n += gridDim.x * 256) {
        const float px = points[3*n], py = points[3*n+1], pz = points[3*n+2];
        float v[CI];
#pragma unroll
        for (int o = 0; o < CI; ++o) {
            float t = Ws[o*CC+20] * px;
            t = fmaf(Ws[o*CC+21], py, t);
            v[o] = fmaf(Ws[o*CC+22], pz, t);
        }
        int idx[KNN_];
#pragma unroll
        for (int k = 0; k < KNN_; ++k) idx[k] = index[n * KNN_ + k];

#pragma unroll 1
        for (int t = 0; t < 4; ++t) {
            float ra[CI], rb[CI];
            loadrow20h(u + (size_t)idx[2*t]   * USH, ra);
            loadrow20h(u + (size_t)idx[2*t+1] * USH, rb);
#pragma unroll
            for (int o = 0; o < CI; ++o) {
                const float d = ra[o] - v[o];
                acc[o] += d;
                acc[CI + o] = fmaf(d, d, acc[CI + o]);
            }
#pragma unroll
            for (int o = 0; o < CI; ++o) {
                const float d = rb[o] - v[o];
                acc[o] += d;
                acc[CI + o] = fmaf(d, d, acc[CI + o]);
            }
        }
        {   // k = 8 tail
            float ra[CI];
            loadrow20h(u + (size_t)idx[8] * USH, ra);
#pragma unroll
            for (int o = 0; o < CI; ++o) {
                const float d = ra[o] - v[o];
                acc[o] += d;
                acc[CI + o] = fmaf(d, d, acc[CI + o]);
            }
        }
    }
    __syncthreads();
    block_reduce_add<2 * CI>(acc, stats, red);
}

// ---- K3: xk = u[j]*sc - v2[n]; w_k = xk·x0; xagg = Σ xk w_k ----
__global__ __launch_bounds__(256, 3) void k3_attn(
    const float* __restrict__ points, const int* __restrict__ index,
    const float* __restrict__ W1, const float* __restrict__ g1,
    const float* __restrict__ b1, const double* __restrict__ stats,
    const __half* __restrict__ u,
    float* __restrict__ wbuf, float* __restrict__ xagg, int as, int N)
{
    __shared__ float Ws[CI * CC];
    __shared__ float sc[CI], sh[CI];
    for (int i = threadIdx.x; i < CI * CC; i += 256) Ws[i] = W1[i];
    if (threadIdx.x < CI) {
        const double M = (double)N * KNN_;
        const double mean = stats[threadIdx.x] / M;
        const double var  = stats[CI + threadIdx.x] / M - mean * mean;
        const float s = g1[threadIdx.x] * rsqrtf((float)var + EPS);
        sc[threadIdx.x] = s;
        sh[threadIdx.x] = b1[threadIdx.x] - (float)mean * s;
    }
    __syncthreads();

    const int n = blockIdx.x * 256 + threadIdx.x;
    if (n >= N) return;

    const float px = points[3*n], py = points[3*n+1], pz = points[3*n+2];
    float v2[CI];   // v*sc - sh, so xk = u*sc - v2
#pragma unroll
    for (int o = 0; o < CI; ++o) {
        float t = Ws[o*CC+20] * px;
        t = fmaf(Ws[o*CC+21], py, t);
        t = fmaf(Ws[o*CC+22], pz, t);
        v2[o] = fmaf(t, sc[o], -sh[o]);
    }
    int idx[KNN_];
#pragma unroll
    for (int k = 0; k < KNN_; ++k) idx[k] = index[n * KNN_ + k];

    float x0[CI], accv[CI];
    {   // k = 0
        float r[CI];
        loadrow20h(u + (size_t)idx[0] * USH, r);
        float w0 = 0.f;
#pragma unroll
        for (int o = 0; o < CI; ++o) x0[o] = fmaf(r[o], sc[o], -v2[o]);
#pragma unroll
        for (int o = 0; o < CI; ++o) w0 = fmaf(x0[o], x0[o], w0);
        wbuf[n * KNN_] = w0;
#pragma unroll
        for (int o = 0; o < CI; ++o) accv[o] = x0[o] * w0;
    }
#pragma unroll 1
    for (int t = 0; t < 4; ++t) {
        const int ka = 1 + 2*t, kb = 2 + 2*t;
        float ra[CI], rb[CI];
        loadrow20h(u + (size_t)idx[ka] * USH, ra);
        loadrow20h(u + (size_t)idx[kb] * USH, rb);
        float wa = 0.f, wb = 0.f;
#pragma unroll
        for (int o = 0; o < CI; ++o) {
            ra[o] = fmaf(ra[o], sc[o], -v2[o]);
            wa = fmaf(ra[o], x0[o], wa);
        }
#pragma unroll
        for (int o = 0; o < CI; ++o) {
            rb[o] = fmaf(rb[o], sc[o], -v2[o]);
            wb = fmaf(rb[o], x0[o], wb);
        }
        wbuf[n * KNN_ + ka] = wa;
        wbuf[n * KNN_ + kb] = wb;
#pragma unroll
        for (int o = 0; o < CI; ++o) accv[o] = fmaf(ra[o], wa, accv[o]);
#pragma unroll
        for (int o = 0; o < CI; ++o) accv[o] = fmaf(rb[o], wb, accv[o]);
    }
    storerow20(xagg + (size_t)n * as, accv);
}

// ---- K4: x2[n] = Σ_k xagg[idx[n,k]]·w[n,k]; fused BN2 stats ----
__global__ __launch_bounds__(256, 3) void k4_prop(
    const int* __restrict__ index, const float* __restrict__ wbuf,
    const float* __restrict__ xagg, int as, float* __restrict__ x2,
    double* __restrict__ stats2, int N)
{
    __shared__ float red[4 * 2 * CI];
    float st[2 * CI];
#pragma unroll
    for (int i = 0; i < 2 * CI; ++i) st[i] = 0.f;

#pragma unroll 1
    for (int n = blockIdx.x * 256 + threadIdx.x; n < N; n += gridDim.x * 256) {
        int idx[KNN_];
        float wk[KNN_];
#pragma unroll
        for (int k = 0; k < KNN_; ++k) idx[k] = index[n * KNN_ + k];
#pragma unroll
        for (int k = 0; k < KNN_; ++k) wk[k] = wbuf[n * KNN_ + k];

        float accv[CI];
        {
            float r[CI];
            loadrow20(xagg + (size_t)idx[0] * as, r);
#pragma unroll
            for (int o = 0; o < CI; ++o) accv[o] = r[o] * wk[0];
        }
#pragma unroll 1
        for (int t = 0; t < 4; ++t) {
            const int ka = 1 + 2*t, kb = 2 + 2*t;
            float ra[CI], rb[CI];
            loadrow20(xagg + (size_t)idx[ka] * as, ra);
            loadrow20(xagg + (size_t)idx[kb] * as, rb);
#pragma unroll
            for (int o = 0; o < CI; ++o) accv[o] = fmaf(ra[o], wk[ka], accv[o]);
#pragma unroll
            for (int o = 0; o < CI; ++o) accv[o] = fmaf(rb[o], wk[kb], accv[o]);
        }
        storerow20(x2 + (size_t)n * CI, accv);
#pragma unroll
        for (int o = 0; o < CI; ++o) {
            st[o] += accv[o];
            st[CI + o] = fmaf(accv[o], accv[o], st[CI + o]);
        }
    }
    __syncthreads();
    block_reduce_add<2 * CI>(st, stats2, red);
}

// ---- K6: h=relu(bn2(x2)); ybuf = Wr1@[h,feature]+br1 ----
// R7: k0's proven shape — plain (256), one point/thread, two 20x20 dot
// halves sharing in[20]. Live ~50 floats, no arrays with >1-iter liveness.
__global__ __launch_bounds__(256) void k6_refine1(
    const float* __restrict__ x2, const float* __restrict__ feature,
    const float* __restrict__ g2, const float* __restrict__ b2,
    const float* __restrict__ Wr1, const float* __restrict__ br1,
    const double* __restrict__ stats2,
    float* __restrict__ ybuf, int N)
{
    __shared__ float Ws[CI * CAT];
    __shared__ float sc[CI], sh[CI], brs[CI];
    for (int i = threadIdx.x; i < CI * CAT; i += 256) Ws[i] = Wr1[i];
    if (threadIdx.x < CI) {
        const double M = (double)N;
        const double mean = stats2[threadIdx.x] / M;
        const double var  = stats2[CI + threadIdx.x] / M - mean * mean;
        const float s = g2[threadIdx.x] * rsqrtf((float)var + EPS);
        sc[threadIdx.x] = s;
        sh[threadIdx.x] = b2[threadIdx.x] - (float)mean * s;
        brs[threadIdx.x] = br1[threadIdx.x];
    }
    __syncthreads();

    const int n = blockIdx.x * 256 + threadIdx.x;
    if (n >= N) return;

    float in[CI];
    // phase 1: h = relu(bn2(x2)); yv = br1 + W[:,0:20]·h
    loadrow20(x2 + (size_t)n * CI, in);
#pragma unroll
    for (int o = 0; o < CI; ++o)
        in[o] = fmaxf(fmaf(in[o], sc[o], sh[o]), 0.f);
    float yv[CI];
#pragma unroll
    for (int o = 0; o < CI; ++o) {
        float y = brs[o];
#pragma unroll
        for (int c = 0; c < CI; ++c) y = fmaf(Ws[o * CAT + c], in[c], y);
        yv[o] = y;
    }
    // phase 2: yv += W[:,20:40]·feature
    loadrow20(feature + (size_t)n * CI, in);
#pragma unroll
    for (int o = 0; o < CI; ++o) {
        float y = yv[o];
#pragma unroll
        for (int c = 0; c < CI; ++c) y = fmaf(Ws[o * CAT + CI + c], in[c], y);
        yv[o] = y;
    }
    storerow20(ybuf + (size_t)n * CI, yv);
}

// ---- K7: BN3 stats over ybuf (pure streaming, 80 MB) ----
__global__ __launch_bounds__(256) void k7_stats3(
    const float* __restrict__ ybuf, double* __restrict__ stats3, int N)
{
    __shared__ float red[4 * 2 * CI];
    float st[2 * CI];
#pragma unroll
    for (int i = 0; i < 2 * CI; ++i) st[i] = 0.f;

#pragma unroll 1
    for (int n = blockIdx.x * 256 + threadIdx.x; n < N; n += gridDim.x * 256) {
        float yv[CI];
        loadrow20(ybuf + (size_t)n * CI, yv);
#pragma unroll
        for (int o = 0; o < CI; ++o) {
            st[o] += yv[o];
            st[CI + o] = fmaf(yv[o], yv[o], st[CI + o]);
        }
    }
    __syncthreads();
    block_reduce_add<2 * CI>(st, stats3, red);
}

// ---- K8: out = relu(bn3(y)) @ Wr2.T + br2 ----
__global__ __launch_bounds__(256) void k8_out(
    const float* __restrict__ ybuf,
    const float* __restrict__ g3, const float* __restrict__ b3,
    const float* __restrict__ Wr2, const float* __restrict__ br2,
    const double* __restrict__ stats3, float* __restrict__ out, int N)
{
    __shared__ float Ws[CI * CI];
    __shared__ float sc[CI], sh[CI];
    for (int i = threadIdx.x; i < CI * CI; i += 256) Ws[i] = Wr2[i];
    if (threadIdx.x < CI) {
        const double M = (double)N;
        const double mean = stats3[threadIdx.x] / M;
        const double var  = stats3[CI + threadIdx.x] / M - mean * mean;
        const float s = g3[threadIdx.x] * rsqrtf((float)var + EPS);
        sc[threadIdx.x] = s;
        sh[threadIdx.x] = b3[threadIdx.x] - (float)mean * s;
    }
    __syncthreads();

    const int n = blockIdx.x * 256 + threadIdx.x;
    if (n >= N) return;

    float z[CI];
    {
        float yi[CI];
        loadrow20(ybuf + (size_t)n * CI, yi);
#pragma unroll
        for (int o = 0; o < CI; ++o)
            z[o] = fmaxf(fmaf(yi[o], sc[o], sh[o]), 0.f);
    }
    float ov[CI];
#pragma unroll
    for (int o = 0; o < CI; ++o) {
        float y = br2[o];
#pragma unroll
        for (int c = 0; c < CI; ++c) y = fmaf(Ws[o * CI + c], z[c], y);
        ov[o] = y;
    }
    storerow20(out + (size_t)n * CI, ov);
}

extern "C" void kernel_launch(void* const* d_in, const int* in_sizes, int n_in,
                              void* d_out, int out_size, void* d_ws, size_t ws_size,
                              hipStream_t stream) {
    const float* points  = (const float*)d_in[0];
    const float* feature = (const float*)d_in[1];
    const int*   index   = (const int*)  d_in[2];
    const float* W1      = (const float*)d_in[3];
    const float* g1      = (const float*)d_in[4];
    const float* b1      = (const float*)d_in[5];
    const float* g2      = (const float*)d_in[6];
    const float* b2      = (const float*)d_in[7];
    const float* Wr1     = (const float*)d_in[8];
    const float* br1     = (const float*)d_in[9];
    const float* g3      = (const float*)d_in[10];
    const float* b3      = (const float*)d_in[11];
    const float* Wr2     = (const float*)d_in[12];
    const float* br2     = (const float*)d_in[13];
    const int N = in_sizes[0] / 3;
    float* out = (float*)d_out;

    // ws layout: [stats 1KB][wbuf N*9 f32 = 36MB][u fp16 N*32h = 64MB, region
    // sized 80MB so x2 (f32, N*20) can alias it after k3][xagg f32 N*32
    // padded = 128MB]. ybuf aliases xagg (dead after k4).
    // Total = 1KB + 36 + 80 + 128 = 244 MB (R4's padded layout needed 292).
    const int as = 32;   // xagg row stride in floats (128-B line)

    double* stats = (double*)d_ws;
    char* base = (char*)d_ws;
    size_t off = 1024;
    float*  wbuf = (float*)(base + off); off += (size_t)N * KNN_ * 4;
    __half* u    = (__half*)(base + off);
    float*  x2   = (float*)(base + off); off += (size_t)N * CI * 4;  // 80 MB region (u uses first 64)
    float*  xagg = (float*)(base + off);
    float*  ybuf = xagg;  // alias: xagg dead after k4

    hipMemsetAsync(stats, 0, 6 * CI * sizeof(double), stream);

    const int B = 256;
    const int gridN = (N + B - 1) / B;
    k0_uv     <<<gridN, B, 0, stream>>>(points, feature, W1, u, N);
    k1_stats  <<<2048, B, 0, stream>>>(points, index, W1, u, stats, N);
    k3_attn   <<<gridN, B, 0, stream>>>(points, index, W1, g1, b1, stats, u, wbuf, xagg, as, N);
    k4_prop   <<<2048, B, 0, stream>>>(index, wbuf, xagg, as, x2, stats + 2 * CI, N);
    k6_refine1<<<gridN, B, 0, stream>>>(x2, feature, g2, b2, Wr1, br1, stats + 2 * CI, ybuf, N);
    k7_stats3 <<<2048, B, 0, stream>>>(ybuf, stats + 4 * CI, N);
    k8_out    <<<gridN, B, 0, stream>>>(ybuf, g3, b3, Wr2, br2, stats + 4 * CI, out, N);
}

// Round 7
// 949.192 us; speedup vs baseline: 1.2954x; 1.0265x over previous
//
#include <hip/hip_runtime.h>
#include <hip/hip_fp16.h>

// Attention2: point-cloud attention, N=1M, KNN=9, C_in=C_inner=20, REPEAT=2.
// R4: conv1 is affine -> y[n,k] = u[idx]-v[n]; u precomputed (k0), v cheap.
// R5 FAILED: array-ref helper -> scratch (2.3 GB phantom traffic).
// R6 FAILED: cat[40] under (256,3) demoted to scratch (VGPR=84, 1.9 GB).
// R7 WIN: k6 on k0's proven shape -> k6 805 -> ~55 us; total 1043 us.
// R8 FAILED: compact 80-B rows -> line straddle, k3 fetch 590->857 MB.
// R9 WIN: fp16 u in 64-B slots -> 974 us. Model sharpened:
//   - k3 FETCH 578 MB = 9M x 64 B exactly: every random gather costs ONE
//     64-B sector regardless of payload (40 B fp16 vs 80 B fp32 both ~580).
//     Fetch per gather pass is FLOORED at ~576 MB.
//   - 4th confirmation of the ~3.55 TB/s random-access ceiling
//     (3.49/3.60/3.57 across layouts). dur == bytes / 3.55 TB/s.
//   - Remaining headroom: WRITE side (k3 256 vs ~164 ideal: partial 128-B
//     xagg slots -> RFO + full-line writeback) and k4's fp32 gather.
// R10 (this round): xagg -> fp16 in FULLY-WRITTEN 64-B slots (data+zero pad).
//   k3: no RFO, xagg writeback 128->64 MB (WRITE 256->~170, dur ->~205).
//   k4: one 64-B sector per gather (FETCH ->~650, dur ->~195).
//   Risk: absmax 0.03125 -> ~0.05; fallback = fp32 xagg w/ full-slot writes.
// Register discipline: (256,3) on gather kernels; streaming matmuls plain
// (256); no array-ref helpers; all array indices compile-time; gather-loop
// structure FROZEN (R5/R6 scratch-demotion lessons).

constexpr int KNN_ = 9;
constexpr int CI   = 20;
constexpr int CC   = 23;
constexpr int CAT  = 40;
constexpr int USH  = 32;   // fp16 row stride in halves (64 B slot)
constexpr float EPS = 1e-5f;

template <int CNT>
__device__ __forceinline__ void block_reduce_add(float (&v)[CNT], double* __restrict__ dst,
                                                 float* __restrict__ lds /*4*CNT floats*/) {
    const int lane = threadIdx.x & 63;
    const int wid  = threadIdx.x >> 6;
#pragma unroll
    for (int i = 0; i < CNT; ++i) {
        float x = v[i];
#pragma unroll
        for (int off = 32; off > 0; off >>= 1) x += __shfl_down(x, off);
        if (lane == 0) lds[wid * CNT + i] = x;
    }
    __syncthreads();
    if (threadIdx.x < CNT) {
        float x = lds[threadIdx.x] + lds[CNT + threadIdx.x] +
                  lds[2 * CNT + threadIdx.x] + lds[3 * CNT + threadIdx.x];
        atomicAdd(dst + threadIdx.x, (double)x);
    }
}

__device__ __forceinline__ void loadrow20(const float* __restrict__ p, float (&v)[CI]) {
    const float4* q = reinterpret_cast<const float4*>(p);
    const float4 a = q[0], b = q[1], c = q[2], d = q[3], e = q[4];
    v[0]=a.x; v[1]=a.y; v[2]=a.z; v[3]=a.w;
    v[4]=b.x; v[5]=b.y; v[6]=b.z; v[7]=b.w;
    v[8]=c.x; v[9]=c.y; v[10]=c.z; v[11]=c.w;
    v[12]=d.x; v[13]=d.y; v[14]=d.z; v[15]=d.w;
    v[16]=e.x; v[17]=e.y; v[18]=e.z; v[19]=e.w;
}

__device__ __forceinline__ void storerow20(float* __restrict__ p, const float (&v)[CI]) {
    float4* q = reinterpret_cast<float4*>(p);
    q[0] = make_float4(v[0],  v[1],  v[2],  v[3]);
    q[1] = make_float4(v[4],  v[5],  v[6],  v[7]);
    q[2] = make_float4(v[8],  v[9],  v[10], v[11]);
    q[3] = make_float4(v[12], v[13], v[14], v[15]);
    q[4] = make_float4(v[16], v[17], v[18], v[19]);
}

__device__ __forceinline__ float2 h2f(unsigned int u) {
    return __half22float2(__builtin_bit_cast(__half2, u));
}

// fp16 row: 20 halves (40 B) at a 64-B-aligned slot. 3 vector loads.
__device__ __forceinline__ void loadrow20h(const __half* __restrict__ p, float (&v)[CI]) {
    const uint4 A = reinterpret_cast<const uint4*>(p)[0];   // halves 0..7
    const uint4 B = reinterpret_cast<const uint4*>(p)[1];   // halves 8..15
    const uint2 C = reinterpret_cast<const uint2*>(p)[4];   // halves 16..19
    float2 f;
    f = h2f(A.x); v[0]=f.x;  v[1]=f.y;
    f = h2f(A.y); v[2]=f.x;  v[3]=f.y;
    f = h2f(A.z); v[4]=f.x;  v[5]=f.y;
    f = h2f(A.w); v[6]=f.x;  v[7]=f.y;
    f = h2f(B.x); v[8]=f.x;  v[9]=f.y;
    f = h2f(B.y); v[10]=f.x; v[11]=f.y;
    f = h2f(B.z); v[12]=f.x; v[13]=f.y;
    f = h2f(B.w); v[14]=f.x; v[15]=f.y;
    f = h2f(C.x); v[16]=f.x; v[17]=f.y;
    f = h2f(C.y); v[18]=f.x; v[19]=f.y;
}

__device__ __forceinline__ unsigned int f2h(float a, float b) {
    return __builtin_bit_cast(unsigned int, __float22half2_rn(make_float2(a, b)));
}

// store 20 floats as fp16 + zero-pad to the full 64-B slot (full coverage,
// no read-for-ownership, one clean 64-B writeback).
__device__ __forceinline__ void storerow20h(__half* __restrict__ p, const float (&v)[CI]) {
    uint4* q = reinterpret_cast<uint4*>(p);
    q[0] = make_uint4(f2h(v[0],v[1]),   f2h(v[2],v[3]),   f2h(v[4],v[5]),   f2h(v[6],v[7]));
    q[1] = make_uint4(f2h(v[8],v[9]),   f2h(v[10],v[11]), f2h(v[12],v[13]), f2h(v[14],v[15]));
    q[2] = make_uint4(f2h(v[16],v[17]), f2h(v[18],v[19]), 0u, 0u);
    q[3] = make_uint4(0u, 0u, 0u, 0u);
}

// ---- K0: u[n] = W_f·feat[n] + W_x·p[n] (streamed, once; fp16 out) ----
__global__ __launch_bounds__(256) void k0_uv(
    const float* __restrict__ points, const float* __restrict__ feature,
    const float* __restrict__ W1, __half* __restrict__ u, int N)
{
    __shared__ float Ws[CI * CC];
    for (int i = threadIdx.x; i < CI * CC; i += 256) Ws[i] = W1[i];
    __syncthreads();
    const int n = blockIdx.x * 256 + threadIdx.x;
    if (n >= N) return;
    float in[CI];
    loadrow20(feature + (size_t)n * CI, in);
    const float px = points[3*n], py = points[3*n+1], pz = points[3*n+2];
    float uo[CI];
#pragma unroll
    for (int o = 0; o < CI; ++o) {
        float y = Ws[o*CC+20] * px;
        y = fmaf(Ws[o*CC+21], py, y);
        y = fmaf(Ws[o*CC+22], pz, y);
#pragma unroll
        for (int c = 0; c < CI; ++c) y = fmaf(Ws[o*CC+c], in[c], y);
        uo[o] = y;
    }
    storerow20h(u + (size_t)n * USH, uo);
}

// ---- K1: BN1 stats of y = u[idx[n,k]] - v[n] over all 9M pairs ----
__global__ __launch_bounds__(256, 3) void k1_stats(
    const float* __restrict__ points, const int* __restrict__ index,
    const float* __restrict__ W1, const __half* __restrict__ u,
    double* __restrict__ stats, int N)
{
    __shared__ float Ws[CI * CC];
    __shared__ float red[4 * 2 * CI];
    for (int i = threadIdx.x; i < CI * CC; i += 256) Ws[i] = W1[i];
    __syncthreads();

    float acc[2 * CI];
#pragma unroll
    for (int i = 0; i < 2 * CI; ++i) acc[i] = 0.f;

#pragma unroll 1
    for (int n = blockIdx.x * 256 + threadIdx.x; n < N; n += gridDim.x * 256) {
        const float px = points[3*n], py = points[3*n+1], pz = points[3*n+2];
        float v[CI];
#pragma unroll
        for (int o = 0; o < CI; ++o) {
            float t = Ws[o*CC+20] * px;
            t = fmaf(Ws[o*CC+21], py, t);
            v[o] = fmaf(Ws[o*CC+22], pz, t);
        }
        int idx[KNN_];
#pragma unroll
        for (int k = 0; k < KNN_; ++k) idx[k] = index[n * KNN_ + k];

#pragma unroll 1
        for (int t = 0; t < 4; ++t) {
            float ra[CI], rb[CI];
            loadrow20h(u + (size_t)idx[2*t]   * USH, ra);
            loadrow20h(u + (size_t)idx[2*t+1] * USH, rb);
#pragma unroll
            for (int o = 0; o < CI; ++o) {
                const float d = ra[o] - v[o];
                acc[o] += d;
                acc[CI + o] = fmaf(d, d, acc[CI + o]);
            }
#pragma unroll
            for (int o = 0; o < CI; ++o) {
                const float d = rb[o] - v[o];
                acc[o] += d;
                acc[CI + o] = fmaf(d, d, acc[CI + o]);
            }
        }
        {   // k = 8 tail
            float ra[CI];
            loadrow20h(u + (size_t)idx[8] * USH, ra);
#pragma unroll
            for (int o = 0; o < CI; ++o) {
                const float d = ra[o] - v[o];
                acc[o] += d;
                acc[CI + o] = fmaf(d, d, acc[CI + o]);
            }
        }
    }
    __syncthreads();
    block_reduce_add<2 * CI>(acc, stats, red);
}

// ---- K3: xk = u[j]*sc - v2[n]; w_k = xk·x0; xagg = Σ xk w_k (fp16 out) ----
__global__ __launch_bounds__(256, 3) void k3_attn(
    const float* __restrict__ points, const int* __restrict__ index,
    const float* __restrict__ W1, const float* __restrict__ g1,
    const float* __restrict__ b1, const double* __restrict__ stats,
    const __half* __restrict__ u,
    float* __restrict__ wbuf, __half* __restrict__ xagg, int N)
{
    __shared__ float Ws[CI * CC];
    __shared__ float sc[CI], sh[CI];
    for (int i = threadIdx.x; i < CI * CC; i += 256) Ws[i] = W1[i];
    if (threadIdx.x < CI) {
        const double M = (double)N * KNN_;
        const double mean = stats[threadIdx.x] / M;
        const double var  = stats[CI + threadIdx.x] / M - mean * mean;
        const float s = g1[threadIdx.x] * rsqrtf((float)var + EPS);
        sc[threadIdx.x] = s;
        sh[threadIdx.x] = b1[threadIdx.x] - (float)mean * s;
    }
    __syncthreads();

    const int n = blockIdx.x * 256 + threadIdx.x;
    if (n >= N) return;

    const float px = points[3*n], py = points[3*n+1], pz = points[3*n+2];
    float v2[CI];   // v*sc - sh, so xk = u*sc - v2
#pragma unroll
    for (int o = 0; o < CI; ++o) {
        float t = Ws[o*CC+20] * px;
        t = fmaf(Ws[o*CC+21], py, t);
        t = fmaf(Ws[o*CC+22], pz, t);
        v2[o] = fmaf(t, sc[o], -sh[o]);
    }
    int idx[KNN_];
#pragma unroll
    for (int k = 0; k < KNN_; ++k) idx[k] = index[n * KNN_ + k];

    float x0[CI], accv[CI];
    {   // k = 0
        float r[CI];
        loadrow20h(u + (size_t)idx[0] * USH, r);
        float w0 = 0.f;
#pragma unroll
        for (int o = 0; o < CI; ++o) x0[o] = fmaf(r[o], sc[o], -v2[o]);
#pragma unroll
        for (int o = 0; o < CI; ++o) w0 = fmaf(x0[o], x0[o], w0);
        wbuf[n * KNN_] = w0;
#pragma unroll
        for (int o = 0; o < CI; ++o) accv[o] = x0[o] * w0;
    }
#pragma unroll 1
    for (int t = 0; t < 4; ++t) {
        const int ka = 1 + 2*t, kb = 2 + 2*t;
        float ra[CI], rb[CI];
        loadrow20h(u + (size_t)idx[ka] * USH, ra);
        loadrow20h(u + (size_t)idx[kb] * USH, rb);
        float wa = 0.f, wb = 0.f;
#pragma unroll
        for (int o = 0; o < CI; ++o) {
            ra[o] = fmaf(ra[o], sc[o], -v2[o]);
            wa = fmaf(ra[o], x0[o], wa);
        }
#pragma unroll
        for (int o = 0; o < CI; ++o) {
            rb[o] = fmaf(rb[o], sc[o], -v2[o]);
            wb = fmaf(rb[o], x0[o], wb);
        }
        wbuf[n * KNN_ + ka] = wa;
        wbuf[n * KNN_ + kb] = wb;
#pragma unroll
        for (int o = 0; o < CI; ++o) accv[o] = fmaf(ra[o], wa, accv[o]);
#pragma unroll
        for (int o = 0; o < CI; ++o) accv[o] = fmaf(rb[o], wb, accv[o]);
    }
    storerow20h(xagg + (size_t)n * USH, accv);
}

// ---- K4: x2[n] = Σ_k xagg[idx[n,k]]·w[n,k]; fused BN2 stats ----
__global__ __launch_bounds__(256, 3) void k4_prop(
    const int* __restrict__ index, const float* __restrict__ wbuf,
    const __half* __restrict__ xagg, float* __restrict__ x2,
    double* __restrict__ stats2, int N)
{
    __shared__ float red[4 * 2 * CI];
    float st[2 * CI];
#pragma unroll
    for (int i = 0; i < 2 * CI; ++i) st[i] = 0.f;

#pragma unroll 1
    for (int n = blockIdx.x * 256 + threadIdx.x; n < N; n += gridDim.x * 256) {
        int idx[KNN_];
        float wk[KNN_];
#pragma unroll
        for (int k = 0; k < KNN_; ++k) idx[k] = index[n * KNN_ + k];
#pragma unroll
        for (int k = 0; k < KNN_; ++k) wk[k] = wbuf[n * KNN_ + k];

        float accv[CI];
        {
            float r[CI];
            loadrow20h(xagg + (size_t)idx[0] * USH, r);
#pragma unroll
            for (int o = 0; o < CI; ++o) accv[o] = r[o] * wk[0];
        }
#pragma unroll 1
        for (int t = 0; t < 4; ++t) {
            const int ka = 1 + 2*t, kb = 2 + 2*t;
            float ra[CI], rb[CI];
            loadrow20h(xagg + (size_t)idx[ka] * USH, ra);
            loadrow20h(xagg + (size_t)idx[kb] * USH, rb);
#pragma unroll
            for (int o = 0; o < CI; ++o) accv[o] = fmaf(ra[o], wk[ka], accv[o]);
#pragma unroll
            for (int o = 0; o < CI; ++o) accv[o] = fmaf(rb[o], wk[kb], accv[o]);
        }
        storerow20(x2 + (size_t)n * CI, accv);
#pragma unroll
        for (int o = 0; o < CI; ++o) {
            st[o] += accv[o];
            st[CI + o] = fmaf(accv[o], accv[o], st[CI + o]);
        }
    }
    __syncthreads();
    block_reduce_add<2 * CI>(st, stats2, red);
}

// ---- K6: h=relu(bn2(x2)); ybuf = Wr1@[h,feature]+br1 ----
// R7: k0's proven shape — plain (256), one point/thread, two 20x20 dot
// halves sharing in[20]. Live ~50 floats, no arrays with >1-iter liveness.
__global__ __launch_bounds__(256) void k6_refine1(
    const float* __restrict__ x2, const float* __restrict__ feature,
    const float* __restrict__ g2, const float* __restrict__ b2,
    const float* __restrict__ Wr1, const float* __restrict__ br1,
    const double* __restrict__ stats2,
    float* __restrict__ ybuf, int N)
{
    __shared__ float Ws[CI * CAT];
    __shared__ float sc[CI], sh[CI], brs[CI];
    for (int i = threadIdx.x; i < CI * CAT; i += 256) Ws[i] = Wr1[i];
    if (threadIdx.x < CI) {
        const double M = (double)N;
        const double mean = stats2[threadIdx.x] / M;
        const double var  = stats2[CI + threadIdx.x] / M - mean * mean;
        const float s = g2[threadIdx.x] * rsqrtf((float)var + EPS);
        sc[threadIdx.x] = s;
        sh[threadIdx.x] = b2[threadIdx.x] - (float)mean * s;
        brs[threadIdx.x] = br1[threadIdx.x];
    }
    __syncthreads();

    const int n = blockIdx.x * 256 + threadIdx.x;
    if (n >= N) return;

    float in[CI];
    // phase 1: h = relu(bn2(x2)); yv = br1 + W[:,0:20]·h
    loadrow20(x2 + (size_t)n * CI, in);
#pragma unroll
    for (int o = 0; o < CI; ++o)
        in[o] = fmaxf(fmaf(in[o], sc[o], sh[o]), 0.f);
    float yv[CI];
#pragma unroll
    for (int o = 0; o < CI; ++o) {
        float y = brs[o];
#pragma unroll
        for (int c = 0; c < CI; ++c) y = fmaf(Ws[o * CAT + c], in[c], y);
        yv[o] = y;
    }
    // phase 2: yv += W[:,20:40]·feature
    loadrow20(feature + (size_t)n * CI, in);
#pragma unroll
    for (int o = 0; o < CI; ++o) {
        float y = yv[o];
#pragma unroll
        for (int c = 0; c < CI; ++c) y = fmaf(Ws[o * CAT + CI + c], in[c], y);
        yv[o] = y;
    }
    storerow20(ybuf + (size_t)n * CI, yv);
}

// ---- K7: BN3 stats over ybuf (pure streaming, 80 MB) ----
__global__ __launch_bounds__(256) void k7_stats3(
    const float* __restrict__ ybuf, double* __restrict__ stats3, int N)
{
    __shared__ float red[4 * 2 * CI];
    float st[2 * CI];
#pragma unroll
    for (int i = 0; i < 2 * CI; ++i) st[i] = 0.f;

#pragma unroll 1
    for (int n = blockIdx.x * 256 + threadIdx.x; n < N; n += gridDim.x * 256) {
        float yv[CI];
        loadrow20(ybuf + (size_t)n * CI, yv);
#pragma unroll
        for (int o = 0; o < CI; ++o) {
            st[o] += yv[o];
            st[CI + o] = fmaf(yv[o], yv[o], st[CI + o]);
        }
    }
    __syncthreads();
    block_reduce_add<2 * CI>(st, stats3, red);
}

// ---- K8: out = relu(bn3(y)) @ Wr2.T + br2 ----
__global__ __launch_bounds__(256) void k8_out(
    const float* __restrict__ ybuf,
    const float* __restrict__ g3, const float* __restrict__ b3,
    const float* __restrict__ Wr2, const float* __restrict__ br2,
    const double* __restrict__ stats3, float* __restrict__ out, int N)
{
    __shared__ float Ws[CI * CI];
    __shared__ float sc[CI], sh[CI];
    for (int i = threadIdx.x; i < CI * CI; i += 256) Ws[i] = Wr2[i];
    if (threadIdx.x < CI) {
        const double M = (double)N;
        const double mean = stats3[threadIdx.x] / M;
        const double var  = stats3[CI + threadIdx.x] / M - mean * mean;
        const float s = g3[threadIdx.x] * rsqrtf((float)var + EPS);
        sc[threadIdx.x] = s;
        sh[threadIdx.x] = b3[threadIdx.x] - (float)mean * s;
    }
    __syncthreads();

    const int n = blockIdx.x * 256 + threadIdx.x;
    if (n >= N) return;

    float z[CI];
    {
        float yi[CI];
        loadrow20(ybuf + (size_t)n * CI, yi);
#pragma unroll
        for (int o = 0; o < CI; ++o)
            z[o] = fmaxf(fmaf(yi[o], sc[o], sh[o]), 0.f);
    }
    float ov[CI];
#pragma unroll
    for (int o = 0; o < CI; ++o) {
        float y = br2[o];
#pragma unroll
        for (int c = 0; c < CI; ++c) y = fmaf(Ws[o * CI + c], z[c], y);
        ov[o] = y;
    }
    storerow20(out + (size_t)n * CI, ov);
}

extern "C" void kernel_launch(void* const* d_in, const int* in_sizes, int n_in,
                              void* d_out, int out_size, void* d_ws, size_t ws_size,
                              hipStream_t stream) {
    const float* points  = (const float*)d_in[0];
    const float* feature = (const float*)d_in[1];
    const int*   index   = (const int*)  d_in[2];
    const float* W1      = (const float*)d_in[3];
    const float* g1      = (const float*)d_in[4];
    const float* b1      = (const float*)d_in[5];
    const float* g2      = (const float*)d_in[6];
    const float* b2      = (const float*)d_in[7];
    const float* Wr1     = (const float*)d_in[8];
    const float* br1     = (const float*)d_in[9];
    const float* g3      = (const float*)d_in[10];
    const float* b3      = (const float*)d_in[11];
    const float* Wr2     = (const float*)d_in[12];
    const float* br2     = (const float*)d_in[13];
    const int N = in_sizes[0] / 3;
    float* out = (float*)d_out;

    // ws layout (all regions 80 MB to allow fp32 aliases):
    //   [stats 1KB][wbuf N*9 f32 = 36MB]
    //   [region A 80MB: u fp16 (64MB used) -> x2 f32 (80MB) after k3]
    //   [region B 80MB: xagg fp16 (64MB used) -> ybuf f32 (80MB) after k4]
    // Total = 1KB + 36 + 80 + 80 = 196 MB.
    double* stats = (double*)d_ws;
    char* base = (char*)d_ws;
    size_t off = 1024;
    float*  wbuf = (float*)(base + off); off += (size_t)N * KNN_ * 4;
    __half* u    = (__half*)(base + off);
    float*  x2   = (float*)(base + off); off += (size_t)N * CI * 4;  // 80 MB region
    __half* xagg = (__half*)(base + off);
    float*  ybuf = (float*)(base + off);  // alias: xagg dead after k4

    hipMemsetAsync(stats, 0, 6 * CI * sizeof(double), stream);

    const int B = 256;
    const int gridN = (N + B - 1) / B;
    k0_uv     <<<gridN, B, 0, stream>>>(points, feature, W1, u, N);
    k1_stats  <<<2048, B, 0, stream>>>(points, index, W1, u, stats, N);
    k3_attn   <<<gridN, B, 0, stream>>>(points, index, W1, g1, b1, stats, u, wbuf, xagg, N);
    k4_prop   <<<2048, B, 0, stream>>>(index, wbuf, xagg, x2, stats + 2 * CI, N);
    k6_refine1<<<gridN, B, 0, stream>>>(x2, feature, g2, b2, Wr1, br1, stats + 2 * CI, ybuf, N);
    k7_stats3 <<<2048, B, 0, stream>>>(ybuf, stats + 4 * CI, N);
    k8_out    <<<gridN, B, 0, stream>>>(ybuf, g3, b3, Wr2, br2, stats + 4 * CI, out, N);
}